// Round 4
// baseline (128.981 us; speedup 1.0000x reference)
//
#include <hip/hip_runtime.h>

// CrossAttention with a single global token: K and V rows are identical per
// batch, so softmax is exactly uniform and the output collapses to
//   out[b, n, :] = (g[b] @ Wv + bv) @ Wo + bo        (independent of x, n)
// i.e. one 512-float row per batch broadcast across N=4096 positions.
//
// R4: same fused design as R3; fix = use a Clang ext_vector_type for the
// nontemporal store (HIP_vector_type float4 is a struct and is rejected).

#define BATCH      8
#define NPTS       4096
#define LOCAL_DIM  512
#define GLOBAL_DIM 128
#define HIDDEN_DIM 256

typedef float vfloat4 __attribute__((ext_vector_type(4)));

// Grid: 8 b x 8 jc (64 cols each) x 8 nc (512 rows each) = 512 blocks.
__global__ __launch_bounds__(256) void cross_attn_fused(
        const float* __restrict__ g,
        const float* __restrict__ Wv,
        const float* __restrict__ bv,
        const float* __restrict__ Wo,
        const float* __restrict__ bo,
        vfloat4* __restrict__ out4) {
    __shared__ float   gsh[GLOBAL_DIM];
    __shared__ float   Vsh[HIDDEN_DIM];
    __shared__ float   partial[4][64];
    __shared__ vfloat4 row4sh[16];         // 64 floats of the row slice

    const int blk = blockIdx.x;
    const int b  = blk >> 6;               // 0..7
    const int jc = (blk >> 3) & 7;         // 0..7 -> j0 = jc*64
    const int nc = blk & 7;                // 0..7 -> n0 = nc*512
    const int t  = threadIdx.x;            // 0..255

    if (t < GLOBAL_DIM) gsh[t] = g[b * GLOBAL_DIM + t];
    __syncthreads();

    // V[h] = bv[h] + g[b,:] . Wv[:,h]   (thread t owns h = t; coalesced Wv)
    {
        float acc = bv[t];
        #pragma unroll 16
        for (int d = 0; d < GLOBAL_DIM; ++d)
            acc += gsh[d] * Wv[d * HIDDEN_DIM + t];
        Vsh[t] = acc;
    }
    __syncthreads();

    // row[j] = bo[j] + V . Wo[:, j] for j in [jc*64, jc*64+64).
    // Thread t: j = j0 + (t&63), h-range [(t>>6)*64, +64). 4 partials per j.
    {
        const int j  = jc * 64 + (t & 63);
        const int h0 = (t >> 6) * 64;
        float p = 0.f;
        #pragma unroll 8
        for (int hh = 0; hh < 64; ++hh) {
            const int h = h0 + hh;
            p += Vsh[h] * Wo[h * LOCAL_DIM + j];
        }
        partial[t >> 6][t & 63] = p;
    }
    __syncthreads();

    if (t < 64) {
        float r = bo[jc * 64 + t];
        #pragma unroll
        for (int q = 0; q < 4; ++q) r += partial[q][t];
        ((float*)row4sh)[t] = r;
    }
    __syncthreads();

    // Broadcast: n in [nc*512, nc*512+512), 16 float4 per n.
    // Thread t: fixed j4 = t&15 (row value held in a register), n-lane t>>4.
    const vfloat4 rv = row4sh[t & 15];
    const int   j4   = jc * 16 + (t & 15);        // float4 column index
    const int   nlan = t >> 4;                    // 0..15
    const int   base = (b * NPTS + nc * 512 + nlan) * (LOCAL_DIM / 4) + j4;

    #pragma unroll 8
    for (int it = 0; it < 32; ++it) {
        // n advances by 16 per iter -> address advances by 16*128 float4
        __builtin_nontemporal_store(rv, out4 + base + it * 16 * (LOCAL_DIM / 4));
    }
}

// ---------------------------------------------------------------------------
extern "C" void kernel_launch(void* const* d_in, const int* in_sizes, int n_in,
                              void* d_out, int out_size, void* d_ws, size_t ws_size,
                              hipStream_t stream) {
    // setup_inputs order: 0:x 1:g 2:Wq 3:bq 4:Wk 5:bk 6:Wv 7:bv 8:Wo 9:bo
    const float* g  = (const float*)d_in[1];
    const float* Wv = (const float*)d_in[6];
    const float* bv = (const float*)d_in[7];
    const float* Wo = (const float*)d_in[8];
    const float* bo = (const float*)d_in[9];

    cross_attn_fused<<<512, 256, 0, stream>>>(g, Wv, bv, Wo, bo,
                                              (vfloat4*)d_out);
}

// Round 5
// 125.976 us; speedup vs baseline: 1.0239x; 1.0239x over previous
//
#include <hip/hip_runtime.h>

// CrossAttention with a single global token: K and V rows are identical per
// batch, so softmax is exactly uniform and the output collapses to
//   out[b, n, :] = (g[b] @ Wv + bv) @ Wo + bo        (independent of x, n)
// i.e. one 512-float row per batch broadcast across N=4096 positions.
//
// R5: fused single kernel (R4 structure) but PLAIN stores instead of
// nontemporal. R4 post-mortem: nt-flagged stores bypass L2/L3 and force the
// 64 MiB output to drain to HBM inside the kernel (~10 us); plain stores
// complete into the 256 MiB Infinity Cache (>30 TB/s) and drain lazily,
// which is why R2's plain-store bcast beat the nt fused version by ~3 us.

#define BATCH      8
#define NPTS       4096
#define LOCAL_DIM  512
#define GLOBAL_DIM 128
#define HIDDEN_DIM 256

typedef float vfloat4 __attribute__((ext_vector_type(4)));

// Grid: 8 b x 8 jc (64 cols each) x 8 nc (512 rows each) = 512 blocks.
__global__ __launch_bounds__(256) void cross_attn_fused(
        const float* __restrict__ g,
        const float* __restrict__ Wv,
        const float* __restrict__ bv,
        const float* __restrict__ Wo,
        const float* __restrict__ bo,
        vfloat4* __restrict__ out4) {
    __shared__ float   gsh[GLOBAL_DIM];
    __shared__ float   Vsh[HIDDEN_DIM];
    __shared__ float   partial[4][64];
    __shared__ vfloat4 row4sh[16];         // 64 floats of the row slice

    const int blk = blockIdx.x;
    const int b  = blk >> 6;               // 0..7
    const int jc = (blk >> 3) & 7;         // 0..7 -> j0 = jc*64
    const int nc = blk & 7;                // 0..7 -> n0 = nc*512
    const int t  = threadIdx.x;            // 0..255

    if (t < GLOBAL_DIM) gsh[t] = g[b * GLOBAL_DIM + t];
    __syncthreads();

    // V[h] = bv[h] + g[b,:] . Wv[:,h]   (thread t owns h = t; coalesced Wv)
    {
        float acc = bv[t];
        #pragma unroll 16
        for (int d = 0; d < GLOBAL_DIM; ++d)
            acc += gsh[d] * Wv[d * HIDDEN_DIM + t];
        Vsh[t] = acc;
    }
    __syncthreads();

    // row[j] = bo[j] + V . Wo[:, j] for j in [jc*64, jc*64+64).
    // Thread t: j = j0 + (t&63), h-range [(t>>6)*64, +64). 4 partials per j.
    {
        const int j  = jc * 64 + (t & 63);
        const int h0 = (t >> 6) * 64;
        float p = 0.f;
        #pragma unroll 8
        for (int hh = 0; hh < 64; ++hh) {
            const int h = h0 + hh;
            p += Vsh[h] * Wo[h * LOCAL_DIM + j];
        }
        partial[t >> 6][t & 63] = p;
    }
    __syncthreads();

    if (t < 64) {
        float r = bo[jc * 64 + t];
        #pragma unroll
        for (int q = 0; q < 4; ++q) r += partial[q][t];
        ((float*)row4sh)[t] = r;
    }
    __syncthreads();

    // Broadcast: n in [nc*512, nc*512+512), 16 float4 per n.
    // Thread t: fixed j4 = t&15 (row value held in a register), n-lane t>>4.
    const vfloat4 rv = row4sh[t & 15];
    const int   j4   = jc * 16 + (t & 15);        // float4 column index
    const int   nlan = t >> 4;                    // 0..15
    const int   base = (b * NPTS + nc * 512 + nlan) * (LOCAL_DIM / 4) + j4;

    #pragma unroll 8
    for (int it = 0; it < 32; ++it) {
        // n advances by 16 per iter -> address advances by 16*128 float4
        out4[base + it * 16 * (LOCAL_DIM / 4)] = rv;
    }
}

// ---------------------------------------------------------------------------
extern "C" void kernel_launch(void* const* d_in, const int* in_sizes, int n_in,
                              void* d_out, int out_size, void* d_ws, size_t ws_size,
                              hipStream_t stream) {
    // setup_inputs order: 0:x 1:g 2:Wq 3:bq 4:Wk 5:bk 6:Wv 7:bv 8:Wo 9:bo
    const float* g  = (const float*)d_in[1];
    const float* Wv = (const float*)d_in[6];
    const float* bv = (const float*)d_in[7];
    const float* Wo = (const float*)d_in[8];
    const float* bo = (const float*)d_in[9];

    cross_attn_fused<<<512, 256, 0, stream>>>(g, Wv, bv, Wo, bo,
                                              (vfloat4*)d_out);
}